// Round 5
// baseline (1406.877 us; speedup 1.0000x reference)
//
#include <hip/hip_runtime.h>
#include <math.h>

#define K 20
#define KP1 21
#define F 32
#define NNODES 1000000

#define NP1 112896   // 5376*21
#define NP2 5376     // 256*21
#define NP3 256

// ws float offsets: 3 per-layer weight blocks of 16640 floats:
//   +0     M[a][e][h]      (8192)   Wq·Wk fold (feature part)
//   +8192  C[e][h]         (256)    time-part of q folded with cos(phase)
//   +8448  Wv4[e4][d][c]   (4096)   canonical-packed WvT
//   +12544 P4[k4][f][c]    (3072)   Pcat = [Wo@mw1A ; mw1B], packed (stays global/L1)
//   +15616 m4[e4][d][c]    (1024)   mw2T packed (stays global/L1)
#define WBLK 16640
#define OFF_H1 49920
#define OFF_H2 (OFF_H1 + 2 * NP1 * F)
#define OFF_H3 (OFF_H2 + 2 * NP2 * F)

// LDS float offsets (dynamic smem), 16 waves/block
#define LDS_M    0
#define LDS_C    8192
#define LDS_WV4  8448
#define LDS_WAVE 12544   // + w*1648 : kin 1280 | qf 32 | qz 272 ([h*68+e]) | ob 64
#define WV_STRIDE 1648
#define SMEM_FLOATS (LDS_WAVE + 16 * WV_STRIDE)   // 38912 floats = 155648 B

__device__ __forceinline__ int nhash(int node, int j) {
    return (node * 101 + (j + 1) * 7919) % NNODES;   // max ~1.01e8, fits int32
}

__global__ __launch_bounds__(256) void transform_weights(
    const float* __restrict__ Wq, const float* __restrict__ Wk,
    const float* __restrict__ Wv, const float* __restrict__ Wo,
    const float* __restrict__ mw1, const float* __restrict__ mw2,
    const float* __restrict__ phase, float* __restrict__ ws)
{
    const int l = blockIdx.x, tid = threadIdx.x;
    const float* wq = Wq + l * 4096; const float* wk = Wk + l * 4096;
    const float* wv = Wv + l * 4096; const float* wo = Wo + l * 4096;
    const float* m1 = mw1 + l * 3072; const float* m2 = mw2 + l * 1024;
    float* out = ws + l * WBLK;
    // M[a][e][h] = sum_{d in head h} Wq[a][d] * Wk[e][d]
    for (int i = tid; i < 8192; i += 256) {
        const int a = i >> 8, e = (i >> 2) & 63, h = i & 3;
        float s = 0.f;
        for (int t = 0; t < 16; ++t) s += wq[a * 64 + h * 16 + t] * wk[e * 64 + h * 16 + t];
        out[i] = s;
    }
    // C[e][h] = sum_{a time} cos(phase[a]) * M_time[a][e][h]
    for (int i = tid; i < 256; i += 256) {
        const int e = i >> 2, h = i & 3;
        float s = 0.f;
        for (int a = 0; a < 32; ++a) {
            float acc = 0.f;
            for (int t = 0; t < 16; ++t) acc += wq[(32 + a) * 64 + h * 16 + t] * wk[e * 64 + h * 16 + t];
            s += cosf(phase[a]) * acc;
        }
        out[8192 + i] = s;
    }
    // Wv4[e4][d][c] = Wv[4e4+c][d]
    for (int i = tid; i < 4096; i += 256) {
        const int e4 = i >> 8, d = (i >> 2) & 63, c = i & 3;
        out[8448 + i] = wv[(4 * e4 + c) * 64 + d];
    }
    // P4[k4][f][c] = Pc[4k4+c][f]; Pc[k][f] = (k<64) ? (Wo@mw1A)[k][f] : mw1[k][f]
    for (int i = tid; i < 3072; i += 256) {
        const int k4 = i >> 7, f = (i >> 2) & 31, c = i & 3;
        const int k = 4 * k4 + c;
        float v;
        if (k < 64) { v = 0.f; for (int g2 = 0; g2 < 64; ++g2) v += wo[k * 64 + g2] * m1[g2 * 32 + f]; }
        else v = m1[k * 32 + f];
        out[12544 + i] = v;
    }
    // m4[e4][d][c] = mw2[4e4+c][d]
    for (int i = tid; i < 1024; i += 256) {
        const int e4 = i >> 7, d = (i >> 2) & 31, c = i & 3;
        out[15616 + i] = m2[(4 * e4 + c) * 32 + d];
    }
}

template<int LEVEL>
__global__ __launch_bounds__(1024) void attn_kernel(
    const int* __restrict__ src_idx, const int* __restrict__ tgt_idx,
    const float* __restrict__ cut_time, const float* __restrict__ emb,
    const float* __restrict__ freq, const float* __restrict__ phase,
    const float* __restrict__ ws_w,
    const float* __restrict__ mb1_, const float* __restrict__ mb2_,
    const float* __restrict__ h_in, float* __restrict__ h_out)
{
    constexpr int NPAIRS = (LEVEL == 1) ? NP1 : (LEVEL == 2 ? NP2 : NP3);
    constexpr int PREVN  = (LEVEL == 2) ? NP1 : NP2;
    constexpr int l = LEVEL - 1;

    extern __shared__ float smem[];

    const int tid  = threadIdx.x;
    const int w    = tid >> 6;        // 0..15
    const int lane = tid & 63;
    const int h    = lane >> 4;
    const int c3   = lane & 7;
    const int rep  = (lane >> 3) & 1;
    const int td   = lane & 31;
    const int half = lane >> 5;

    // ---- stage weights into LDS once per block (M, C, Wv4 only)
    {
        const float* wsrc = ws_w + l * WBLK;
        for (int i4 = tid; i4 < 2112; i4 += 1024)          // M + C
            *(float4*)&smem[i4 * 4] = *(const float4*)&wsrc[i4 * 4];
        for (int i4 = tid; i4 < 1024; i4 += 1024)          // Wv4
            *(float4*)&smem[LDS_WV4 + i4 * 4] = *(const float4*)&wsrc[8448 + i4 * 4];
    }
    __syncthreads();

    float* sM   = smem;
    float* sC   = smem + LDS_C;
    float* sWv4 = smem + LDS_WV4;
    float* kin  = smem + LDS_WAVE + w * WV_STRIDE;   // [j*64 + e]
    float* qfb  = kin + 1280;                        // [32]
    float* qzb  = kin + 1312;                        // [h*68 + e]
    float* obb  = kin + 1584;                        // [64]

    const float* P4g = ws_w + l * WBLK + 12544;      // L1-resident merge weights
    const float* m4g = ws_w + l * WBLK + 15616;

    const float fr = freq[td], ph = phase[td];
    const float b1v = mb1_[l * 32 + td], b2v = mb2_[l * 32 + td];

    const int gstride = gridDim.x * 16;
    float4 pf0, pf1, pf2; int na; float ta;

    auto PRE = [&](int i) {
        const int side = (i >= NPAIRS) ? 1 : 0;
        const int p = i - side * NPAIRS;
        int b, s2 = 0, r = 0;
        if (LEVEL == 3)      { b = p; }
        else if (LEVEL == 2) { b = p / KP1; s2 = p % KP1; }
        else                 { int qq = p / KP1; r = p % KP1; b = qq / KP1; s2 = qq % KP1; }
        const int root = side ? tgt_idx[b] : src_idx[b];
        const float ct = cut_time[b];
        if (LEVEL == 3) { na = root; ta = ct; }
        else if (LEVEL == 2) {
            na = s2 ? nhash(root, s2 - 1) : root;
            ta = s2 ? ct * ((float)s2 / 21.0f) : ct;
        } else {
            const int   n2 = s2 ? nhash(root, s2 - 1) : root;
            const float t2 = s2 ? ct * ((float)s2 / 21.0f) : ct;
            na = r ? nhash(n2, r - 1) : n2;
            ta = r ? t2 * ((float)r / 21.0f) : t2;
        }
        if (LEVEL == 1) {
            { const int row = lane >> 3, c4 = lane & 7;
              const int node = row ? nhash(na, row - 1) : na;
              pf0 = *(const float4*)&emb[(size_t)node * F + c4 * 4]; }
            { const int idx4 = 64 + lane, row = idx4 >> 3, c4 = idx4 & 7;
              const int node = nhash(na, row - 1);
              pf1 = *(const float4*)&emb[(size_t)node * F + c4 * 4]; }
            { const int idx4 = 128 + lane;
              if (idx4 < 168) {
                  const int row = idx4 >> 3, c4 = idx4 & 7;
                  const int node = nhash(na, row - 1);
                  pf2 = *(const float4*)&emb[(size_t)node * F + c4 * 4]; } }
        } else {
            const float* base = h_in + ((size_t)side * PREVN + (size_t)p * KP1) * F;
            pf0 = *(const float4*)&base[lane * 4];
            pf1 = *(const float4*)&base[(64 + lane) * 4];
            if (128 + lane < 168) pf2 = *(const float4*)&base[(128 + lane) * 4];
        }
    };

    int g = blockIdx.x * 16 + w;
    if (g < 2 * NPAIRS) PRE(g);

    for (; g < 2 * NPAIRS; g += gstride) {
        const int curside = (g >= NPAIRS) ? 1 : 0;
        const int curp = g - curside * NPAIRS;
        const int   cna = na;
        const float cta = ta;

        // ---- fill LDS from prefetch regs
        { const int row = lane >> 3, c4 = lane & 7;
          if (row == 0) *(float4*)&qfb[c4 * 4] = pf0;
          else          *(float4*)&kin[(row - 1) * 64 + c4 * 4] = pf0; }
        { const int idx4 = 64 + lane, row = idx4 >> 3, c4 = idx4 & 7;
          *(float4*)&kin[(row - 1) * 64 + c4 * 4] = pf1; }
        { const int idx4 = 128 + lane;
          if (idx4 < 168) { const int row = idx4 >> 3, c4 = idx4 & 7;
            *(float4*)&kin[(row - 1) * 64 + c4 * 4] = pf2; } }

        // ---- time encodings (bit-identical to reference arg chain)
        #pragma unroll
        for (int it = 0; it < 10; ++it) {
            const int j = it * 2 + half;
            const float ngh_t = cta * ((float)(j + 1) / 21.0f);
            const float delta = cta - ngh_t;
            kin[j * 64 + 32 + td] = cosf(delta * fr + ph);
        }
        // ---- mask bits (incremental mod)
        unsigned mbits = 0;
        { int m = (cna * 101 + 7919) % NNODES;
          #pragma unroll
          for (int j = 0; j < K; ++j) {
              if (m == 0) mbits |= (1u << j);
              m += 7919; if (m >= NNODES) m -= NNODES;
          } }

        if (g + gstride < 2 * NPAIRS) PRE(g + gstride);

        // ---- QK phase: lane = e; qk_h[e] = C[e][h] + sum_a feat[a]*M[a][e][h]
        float4 acc = *(const float4*)&sC[lane * 4];
        #pragma unroll
        for (int a4 = 0; a4 < 8; ++a4) {
            const float4 f4 = *(float4*)&qfb[a4 * 4];
            const float4 m0 = *(const float4*)&sM[(a4 * 4 + 0) * 256 + lane * 4];
            const float4 m1v = *(const float4*)&sM[(a4 * 4 + 1) * 256 + lane * 4];
            const float4 m2v = *(const float4*)&sM[(a4 * 4 + 2) * 256 + lane * 4];
            const float4 m3 = *(const float4*)&sM[(a4 * 4 + 3) * 256 + lane * 4];
            acc.x += f4.x * m0.x + f4.y * m1v.x + f4.z * m2v.x + f4.w * m3.x;
            acc.y += f4.x * m0.y + f4.y * m1v.y + f4.z * m2v.y + f4.w * m3.y;
            acc.z += f4.x * m0.z + f4.y * m1v.z + f4.z * m2v.z + f4.w * m3.z;
            acc.w += f4.x * m0.w + f4.y * m1v.w + f4.z * m2v.w + f4.w * m3.w;
        }
        qzb[0 * 68 + lane] = acc.x; qzb[1 * 68 + lane] = acc.y;
        qzb[2 * 68 + lane] = acc.z; qzb[3 * 68 + lane] = acc.w;

        // ---- scores: lane=(h,rep,c3); rep-swapped slice offsets so each
        //      ds_read's 16 addresses tile all 16 bank-quads (conflict fix)
        const int ofsA = c3 * 8 + rep * 4;
        const int ofsB = c3 * 8 + 4 - rep * 4;
        const float4 qkA = *(float4*)&qzb[h * 68 + ofsA];
        const float4 qkB = *(float4*)&qzb[h * 68 + ofsB];
        const int j0 = rep * 10;
        float sc[10];
        #pragma unroll
        for (int t = 0; t < 10; ++t) {
            const float4 kA = *(float4*)&kin[(j0 + t) * 64 + ofsA];
            const float4 kB = *(float4*)&kin[(j0 + t) * 64 + ofsB];
            sc[t] = qkA.x * kA.x + qkA.y * kA.y + qkA.z * kA.z + qkA.w * kA.w
                  + qkB.x * kB.x + qkB.y * kB.y + qkB.z * kB.z + qkB.w * kB.w;
        }
        #pragma unroll
        for (int off = 1; off < 8; off <<= 1) {
            #pragma unroll
            for (int t = 0; t < 10; ++t) sc[t] += __shfl_xor(sc[t], off, 8);
        }
        #pragma unroll
        for (int t = 0; t < 10; ++t) {
            float s = sc[t] * 0.25f;                      // 1/sqrt(16)
            if ((mbits >> (j0 + t)) & 1) s = -1e9f;
            sc[t] = s;
        }
        float mx = sc[0];
        #pragma unroll
        for (int t = 1; t < 10; ++t) mx = fmaxf(mx, sc[t]);
        mx = fmaxf(mx, __shfl_xor(mx, 8, 16));
        float sum = 0.f;
        #pragma unroll
        for (int t = 0; t < 10; ++t) { sc[t] = __expf(sc[t] - mx); sum += sc[t]; }
        sum += __shfl_xor(sum, 8, 16);
        const float inv = 1.0f / sum;
        // z partials over my 10 j's on my two slices, then rep-exchange
        float4 zA = {0, 0, 0, 0}, zB = {0, 0, 0, 0};
        #pragma unroll
        for (int t = 0; t < 10; ++t) {
            const float4 kA = *(float4*)&kin[(j0 + t) * 64 + ofsA];
            const float4 kB = *(float4*)&kin[(j0 + t) * 64 + ofsB];
            zA.x += sc[t] * kA.x; zA.y += sc[t] * kA.y; zA.z += sc[t] * kA.z; zA.w += sc[t] * kA.w;
            zB.x += sc[t] * kB.x; zB.y += sc[t] * kB.y; zB.z += sc[t] * kB.z; zB.w += sc[t] * kB.w;
        }
        // partner (lane^8) holds the other rep: its zB covers my ofsA slice.
        float4 fA, fB;
        fA.x = zA.x + __shfl_xor(zB.x, 8, 16); fA.y = zA.y + __shfl_xor(zB.y, 8, 16);
        fA.z = zA.z + __shfl_xor(zB.z, 8, 16); fA.w = zA.w + __shfl_xor(zB.w, 8, 16);
        fB.x = zB.x + __shfl_xor(zA.x, 8, 16); fB.y = zB.y + __shfl_xor(zA.y, 8, 16);
        fB.z = zB.z + __shfl_xor(zA.z, 8, 16); fB.w = zB.w + __shfl_xor(zA.w, 8, 16);
        fA.x *= inv; fA.y *= inv; fA.z *= inv; fA.w *= inv;
        fB.x *= inv; fB.y *= inv; fB.z *= inv; fB.w *= inv;
        if (rep == 0) {
            *(float4*)&qzb[h * 68 + ofsA] = fA;      // ofsA = c3*8
            *(float4*)&qzb[h * 68 + ofsB] = fB;      // ofsB = c3*8+4
        }

        // ---- OD: lane = d; od = sum_e z_{h(d)}[e] * Wv[e][d]  (canonical Wv4)
        float od = 0.f;
        #pragma unroll
        for (int e4 = 0; e4 < 16; ++e4) {
            const float4 z  = *(float4*)&qzb[h * 68 + e4 * 4];
            const float4 wv = *(float4*)&sWv4[e4 * 256 + lane * 4];
            od += z.x * wv.x + z.y * wv.y + z.z * wv.z + z.w * wv.w;
        }
        obb[lane] = od;

        // ---- merge1 via Pcat (global/L1): hv[f] = [od||feat] @ Pcat[:,f]
        float hv = 0.f;
        #pragma unroll
        for (int e4 = 0; e4 < 12; ++e4) {
            float4 x;
            if (half == 0) x = *(float4*)&obb[e4 * 4];
            else x = (e4 < 4) ? *(float4*)&obb[48 + e4 * 4]
                              : *(float4*)&qfb[(e4 - 4) * 4];
            const float4 w4 = *(const float4*)&P4g[(half * 12 + e4) * 128 + td * 4];
            hv += x.x * w4.x + x.y * w4.y + x.z * w4.z + x.w * w4.w;
        }
        hv += __shfl_xor(hv, 32);
        hv = fmaxf(hv + b1v, 0.0f);
        if (lane < 32) obb[td] = hv;     // alias hidden buffer onto obb[0..31]

        // ---- merge2 (global/L1) + store
        float y = 0.f;
        #pragma unroll
        for (int e4 = 0; e4 < 4; ++e4) {
            const float4 x  = *(float4*)&obb[half * 16 + e4 * 4];
            const float4 w4 = *(const float4*)&m4g[(half * 4 + e4) * 128 + td * 4];
            y += x.x * w4.x + x.y * w4.y + x.z * w4.z + x.w * w4.w;
        }
        y += __shfl_xor(y, 32);
        if (lane < 32)
            h_out[((size_t)curside * NPAIRS + curp) * F + td] = y + b2v;
    }
}

__global__ __launch_bounds__(256) void final_kernel(
    const float* __restrict__ h3,
    const float* __restrict__ aw1, const float* __restrict__ ab1,
    const float* __restrict__ aw2, const float* __restrict__ ab2,
    float* __restrict__ out)
{
    const int bidx = threadIdx.x;   // 256 threads, 1 block
    float x[64];
    #pragma unroll
    for (int e = 0; e < 32; ++e) {
        x[e]      = h3[(size_t)bidx * 32 + e];
        x[32 + e] = h3[((size_t)NP3 + bidx) * 32 + e];
    }
    float acc = ab2[0];
    for (int f = 0; f < 32; ++f) {
        float hv = ab1[f];
        #pragma unroll
        for (int e = 0; e < 64; ++e) hv += x[e] * aw1[e * 32 + f];
        acc += fmaxf(hv, 0.0f) * aw2[f];
    }
    out[bidx] = acc;
}

extern "C" void kernel_launch(void* const* d_in, const int* in_sizes, int n_in,
                              void* d_out, int out_size, void* d_ws, size_t ws_size,
                              hipStream_t stream)
{
    const int*   src_idx = (const int*)d_in[0];
    const int*   tgt_idx = (const int*)d_in[1];
    const float* cut     = (const float*)d_in[2];
    const float* emb   = (const float*)d_in[4];
    const float* freq  = (const float*)d_in[5];
    const float* phase = (const float*)d_in[6];
    const float* Wq    = (const float*)d_in[7];
    const float* Wk    = (const float*)d_in[8];
    const float* Wv    = (const float*)d_in[9];
    const float* Wo    = (const float*)d_in[10];
    const float* mw1   = (const float*)d_in[11];
    const float* mb1   = (const float*)d_in[12];
    const float* mw2   = (const float*)d_in[13];
    const float* mb2   = (const float*)d_in[14];
    const float* aw1   = (const float*)d_in[15];
    const float* ab1   = (const float*)d_in[16];
    const float* aw2   = (const float*)d_in[17];
    const float* ab2   = (const float*)d_in[18];

    float* ws = (float*)d_ws;
    float* h1 = ws + OFF_H1;
    float* h2 = ws + OFF_H2;
    float* h3 = ws + OFF_H3;

    const size_t smem_bytes = SMEM_FLOATS * sizeof(float);
    hipFuncSetAttribute((const void*)attn_kernel<1>, hipFuncAttributeMaxDynamicSharedMemorySize, (int)smem_bytes);
    hipFuncSetAttribute((const void*)attn_kernel<2>, hipFuncAttributeMaxDynamicSharedMemorySize, (int)smem_bytes);
    hipFuncSetAttribute((const void*)attn_kernel<3>, hipFuncAttributeMaxDynamicSharedMemorySize, (int)smem_bytes);

    transform_weights<<<dim3(3), dim3(256), 0, stream>>>(Wq, Wk, Wv, Wo, mw1, mw2, phase, ws);
    attn_kernel<1><<<dim3(256), dim3(1024), smem_bytes, stream>>>(
        src_idx, tgt_idx, cut, emb, freq, phase, ws, mb1, mb2, (const float*)nullptr, h1);
    attn_kernel<2><<<dim3(256), dim3(1024), smem_bytes, stream>>>(
        src_idx, tgt_idx, cut, emb, freq, phase, ws, mb1, mb2, h1, h2);
    attn_kernel<3><<<dim3(32), dim3(1024), smem_bytes, stream>>>(
        src_idx, tgt_idx, cut, emb, freq, phase, ws, mb1, mb2, h2, h3);
    final_kernel<<<dim3(1), dim3(256), 0, stream>>>(h3, aw1, ab1, aw2, ab2, (float*)d_out);
}

// Round 6
// 721.018 us; speedup vs baseline: 1.9512x; 1.9512x over previous
//
#include <hip/hip_runtime.h>
#include <math.h>

#define K 20
#define KP1 21
#define F 32
#define NNODES 1000000

#define NP1 112896   // 5376*21
#define NP2 5376     // 256*21
#define NP3 256

// ws float offsets: 3 per-layer weight blocks of 16640 floats:
//   +0     M[a][e][h]      (8192)   Wq·Wk fold (feature part)
//   +8192  C[e][h]         (256)    time-part of q folded with cos(phase)
//   +8448  Wv4[e4][d][c]   (4096)   canonical-packed WvT
//   +12544 P4[k4][f][c]    (3072)   Pcat = [Wo@mw1A ; mw1B], packed
//   +15616 m4[e4][d][c]    (1024)   mw2T packed
#define WBLK 16640
#define OFF_H1 49920
#define OFF_H2 (OFF_H1 + 2 * NP1 * F)
#define OFF_H3 (OFF_H2 + 2 * NP2 * F)

// LDS float offsets (dynamic smem), 12 waves/block (768 threads)
#define LDS_WAVE 16640   // + w*1648 : kin 1280 | qf 32 | qz 272 ([h*68+e]) | ob 64
#define WV_STRIDE 1648
#define SMEM_FLOATS (LDS_WAVE + 12 * WV_STRIDE)   // 36416 floats = 145664 B

__device__ __forceinline__ int nhash(int node, int j) {
    return (node * 101 + (j + 1) * 7919) % NNODES;   // max ~1.01e8, fits int32
}

__global__ __launch_bounds__(256) void transform_weights(
    const float* __restrict__ Wq, const float* __restrict__ Wk,
    const float* __restrict__ Wv, const float* __restrict__ Wo,
    const float* __restrict__ mw1, const float* __restrict__ mw2,
    const float* __restrict__ phase, float* __restrict__ ws)
{
    const int l = blockIdx.x, tid = threadIdx.x;
    const float* wq = Wq + l * 4096; const float* wk = Wk + l * 4096;
    const float* wv = Wv + l * 4096; const float* wo = Wo + l * 4096;
    const float* m1 = mw1 + l * 3072; const float* m2 = mw2 + l * 1024;
    float* out = ws + l * WBLK;
    // M[a][e][h] = sum_{d in head h} Wq[a][d] * Wk[e][d]
    for (int i = tid; i < 8192; i += 256) {
        const int a = i >> 8, e = (i >> 2) & 63, h = i & 3;
        float s = 0.f;
        for (int t = 0; t < 16; ++t) s += wq[a * 64 + h * 16 + t] * wk[e * 64 + h * 16 + t];
        out[i] = s;
    }
    // C[e][h] = sum_{a time} cos(phase[a]) * M_time[a][e][h]
    for (int i = tid; i < 256; i += 256) {
        const int e = i >> 2, h = i & 3;
        float s = 0.f;
        for (int a = 0; a < 32; ++a) {
            float acc = 0.f;
            for (int t = 0; t < 16; ++t) acc += wq[(32 + a) * 64 + h * 16 + t] * wk[e * 64 + h * 16 + t];
            s += cosf(phase[a]) * acc;
        }
        out[8192 + i] = s;
    }
    // Wv4[e4][d][c] = Wv[4e4+c][d]
    for (int i = tid; i < 4096; i += 256) {
        const int e4 = i >> 8, d = (i >> 2) & 63, c = i & 3;
        out[8448 + i] = wv[(4 * e4 + c) * 64 + d];
    }
    // P4[k4][f][c] = Pc[4k4+c][f]; Pc[k][f] = (k<64) ? (Wo@mw1A)[k][f] : mw1[k][f]
    for (int i = tid; i < 3072; i += 256) {
        const int k4 = i >> 7, f = (i >> 2) & 31, c = i & 3;
        const int k = 4 * k4 + c;
        float v;
        if (k < 64) { v = 0.f; for (int g2 = 0; g2 < 64; ++g2) v += wo[k * 64 + g2] * m1[g2 * 32 + f]; }
        else v = m1[k * 32 + f];
        out[12544 + i] = v;
    }
    // m4[e4][d][c] = mw2[4e4+c][d]
    for (int i = tid; i < 1024; i += 256) {
        const int e4 = i >> 7, d = (i >> 2) & 31, c = i & 3;
        out[15616 + i] = m2[(4 * e4 + c) * 32 + d];
    }
}

template<int LEVEL>
__global__ __launch_bounds__(768) void attn_kernel(
    const int* __restrict__ src_idx, const int* __restrict__ tgt_idx,
    const float* __restrict__ cut_time, const float* __restrict__ emb,
    const float* __restrict__ freq, const float* __restrict__ phase,
    const float* __restrict__ ws_w,
    const float* __restrict__ mb1_, const float* __restrict__ mb2_,
    const float* __restrict__ h_in, float* __restrict__ h_out)
{
    constexpr int NPAIRS = (LEVEL == 1) ? NP1 : (LEVEL == 2 ? NP2 : NP3);
    constexpr int PREVN  = (LEVEL == 2) ? NP1 : NP2;
    constexpr int l = LEVEL - 1;

    extern __shared__ float smem[];

    const int tid  = threadIdx.x;
    const int w    = tid >> 6;        // 0..11
    const int lane = tid & 63;
    const int h    = lane >> 4;
    const int c3   = lane & 7;
    const int rep  = (lane >> 3) & 1;
    const int td   = lane & 31;
    const int half = lane >> 5;

    // ---- stage all packed weights into LDS once per block (contiguous copy)
    {
        const float* wsrc = ws_w + l * WBLK;
        for (int i4 = tid; i4 < WBLK / 4; i4 += 768)
            *(float4*)&smem[i4 * 4] = *(const float4*)&wsrc[i4 * 4];
    }
    __syncthreads();

    float* sM   = smem;               // [a*256 + e*4 + h]
    float* sC   = smem + 8192;        // [e*4 + h]
    float* sWv4 = smem + 8448;        // [e4*256 + d*4 + c]
    float* sP4  = smem + 12544;       // [k4*128 + f*4 + c]
    float* sm4  = smem + 15616;       // [e4*128 + d*4 + c]
    float* kin  = smem + LDS_WAVE + w * WV_STRIDE;   // [j*64 + e]
    float* qfb  = kin + 1280;                        // [32]
    float* qzb  = kin + 1312;                        // [h*68 + e]
    float* obb  = kin + 1584;                        // [64]

    const float fr = freq[td], ph = phase[td];
    const float b1v = mb1_[l * 32 + td], b2v = mb2_[l * 32 + td];

    const int gstride = gridDim.x * 12;
    float4 pf0, pf1, pf2; int na; float ta;

    auto PRE = [&](int i) {
        const int side = (i >= NPAIRS) ? 1 : 0;
        const int p = i - side * NPAIRS;
        int b, s2 = 0, r = 0;
        if (LEVEL == 3)      { b = p; }
        else if (LEVEL == 2) { b = p / KP1; s2 = p % KP1; }
        else                 { int qq = p / KP1; r = p % KP1; b = qq / KP1; s2 = qq % KP1; }
        const int root = side ? tgt_idx[b] : src_idx[b];
        const float ct = cut_time[b];
        if (LEVEL == 3) { na = root; ta = ct; }
        else if (LEVEL == 2) {
            na = s2 ? nhash(root, s2 - 1) : root;
            ta = s2 ? ct * ((float)s2 / 21.0f) : ct;
        } else {
            const int   n2 = s2 ? nhash(root, s2 - 1) : root;
            const float t2 = s2 ? ct * ((float)s2 / 21.0f) : ct;
            na = r ? nhash(n2, r - 1) : n2;
            ta = r ? t2 * ((float)r / 21.0f) : t2;
        }
        if (LEVEL == 1) {
            { const int row = lane >> 3, c4 = lane & 7;
              const int node = row ? nhash(na, row - 1) : na;
              pf0 = *(const float4*)&emb[(size_t)node * F + c4 * 4]; }
            { const int idx4 = 64 + lane, row = idx4 >> 3, c4 = idx4 & 7;
              const int node = nhash(na, row - 1);
              pf1 = *(const float4*)&emb[(size_t)node * F + c4 * 4]; }
            { const int idx4 = 128 + lane;
              if (idx4 < 168) {
                  const int row = idx4 >> 3, c4 = idx4 & 7;
                  const int node = nhash(na, row - 1);
                  pf2 = *(const float4*)&emb[(size_t)node * F + c4 * 4]; } }
        } else {
            const float* base = h_in + ((size_t)side * PREVN + (size_t)p * KP1) * F;
            pf0 = *(const float4*)&base[lane * 4];
            pf1 = *(const float4*)&base[(64 + lane) * 4];
            if (128 + lane < 168) pf2 = *(const float4*)&base[(128 + lane) * 4];
        }
    };

    int g = blockIdx.x * 12 + w;
    if (g < 2 * NPAIRS) PRE(g);

    for (; g < 2 * NPAIRS; g += gstride) {
        const int curside = (g >= NPAIRS) ? 1 : 0;
        const int curp = g - curside * NPAIRS;
        const int   cna = na;
        const float cta = ta;

        // ---- fill LDS from prefetch regs
        { const int row = lane >> 3, c4 = lane & 7;
          if (row == 0) *(float4*)&qfb[c4 * 4] = pf0;
          else          *(float4*)&kin[(row - 1) * 64 + c4 * 4] = pf0; }
        { const int idx4 = 64 + lane, row = idx4 >> 3, c4 = idx4 & 7;
          *(float4*)&kin[(row - 1) * 64 + c4 * 4] = pf1; }
        { const int idx4 = 128 + lane;
          if (idx4 < 168) { const int row = idx4 >> 3, c4 = idx4 & 7;
            *(float4*)&kin[(row - 1) * 64 + c4 * 4] = pf2; } }

        // ---- time encodings (bit-identical to reference arg chain)
        #pragma unroll
        for (int it = 0; it < 10; ++it) {
            const int j = it * 2 + half;
            const float ngh_t = cta * ((float)(j + 1) / 21.0f);
            const float delta = cta - ngh_t;
            kin[j * 64 + 32 + td] = cosf(delta * fr + ph);
        }
        // ---- mask bits (incremental mod)
        unsigned mbits = 0;
        { int m = (cna * 101 + 7919) % NNODES;
          #pragma unroll
          for (int j = 0; j < K; ++j) {
              if (m == 0) mbits |= (1u << j);
              m += 7919; if (m >= NNODES) m -= NNODES;
          } }

        if (g + gstride < 2 * NPAIRS) PRE(g + gstride);

        // ---- QK phase: lane = e; qk_h[e] = C[e][h] + sum_a feat[a]*M[a][e][h]
        float4 acc = *(const float4*)&sC[lane * 4];
        #pragma unroll
        for (int a4 = 0; a4 < 8; ++a4) {
            const float4 f4 = *(float4*)&qfb[a4 * 4];
            const float4 m0 = *(const float4*)&sM[(a4 * 4 + 0) * 256 + lane * 4];
            const float4 m1v = *(const float4*)&sM[(a4 * 4 + 1) * 256 + lane * 4];
            const float4 m2v = *(const float4*)&sM[(a4 * 4 + 2) * 256 + lane * 4];
            const float4 m3 = *(const float4*)&sM[(a4 * 4 + 3) * 256 + lane * 4];
            acc.x += f4.x * m0.x + f4.y * m1v.x + f4.z * m2v.x + f4.w * m3.x;
            acc.y += f4.x * m0.y + f4.y * m1v.y + f4.z * m2v.y + f4.w * m3.y;
            acc.z += f4.x * m0.z + f4.y * m1v.z + f4.z * m2v.z + f4.w * m3.z;
            acc.w += f4.x * m0.w + f4.y * m1v.w + f4.z * m2v.w + f4.w * m3.w;
        }
        qzb[0 * 68 + lane] = acc.x; qzb[1 * 68 + lane] = acc.y;
        qzb[2 * 68 + lane] = acc.z; qzb[3 * 68 + lane] = acc.w;

        // ---- scores: lane=(h,rep,c3); rep-swapped slice offsets so each
        //      ds_read's 16 addresses tile all 16 bank-quads
        const int ofsA = c3 * 8 + rep * 4;
        const int ofsB = c3 * 8 + 4 - rep * 4;
        const float4 qkA = *(float4*)&qzb[h * 68 + ofsA];
        const float4 qkB = *(float4*)&qzb[h * 68 + ofsB];
        const int j0 = rep * 10;
        float sc[10];
        #pragma unroll
        for (int t = 0; t < 10; ++t) {
            const float4 kA = *(float4*)&kin[(j0 + t) * 64 + ofsA];
            const float4 kB = *(float4*)&kin[(j0 + t) * 64 + ofsB];
            sc[t] = qkA.x * kA.x + qkA.y * kA.y + qkA.z * kA.z + qkA.w * kA.w
                  + qkB.x * kB.x + qkB.y * kB.y + qkB.z * kB.z + qkB.w * kB.w;
        }
        #pragma unroll
        for (int off = 1; off < 8; off <<= 1) {
            #pragma unroll
            for (int t = 0; t < 10; ++t) sc[t] += __shfl_xor(sc[t], off, 8);
        }
        #pragma unroll
        for (int t = 0; t < 10; ++t) {
            float s = sc[t] * 0.25f;                      // 1/sqrt(16)
            if ((mbits >> (j0 + t)) & 1) s = -1e9f;
            sc[t] = s;
        }
        float mx = sc[0];
        #pragma unroll
        for (int t = 1; t < 10; ++t) mx = fmaxf(mx, sc[t]);
        mx = fmaxf(mx, __shfl_xor(mx, 8, 16));
        float sum = 0.f;
        #pragma unroll
        for (int t = 0; t < 10; ++t) { sc[t] = __expf(sc[t] - mx); sum += sc[t]; }
        sum += __shfl_xor(sum, 8, 16);
        const float inv = 1.0f / sum;
        // z partials over my 10 j's on my two slices, then rep-exchange
        float4 zA = {0, 0, 0, 0}, zB = {0, 0, 0, 0};
        #pragma unroll
        for (int t = 0; t < 10; ++t) {
            const float4 kA = *(float4*)&kin[(j0 + t) * 64 + ofsA];
            const float4 kB = *(float4*)&kin[(j0 + t) * 64 + ofsB];
            zA.x += sc[t] * kA.x; zA.y += sc[t] * kA.y; zA.z += sc[t] * kA.z; zA.w += sc[t] * kA.w;
            zB.x += sc[t] * kB.x; zB.y += sc[t] * kB.y; zB.z += sc[t] * kB.z; zB.w += sc[t] * kB.w;
        }
        // partner (lane^8) holds the other rep: its zB covers my ofsA slice.
        float4 fA, fB;
        fA.x = zA.x + __shfl_xor(zB.x, 8, 16); fA.y = zA.y + __shfl_xor(zB.y, 8, 16);
        fA.z = zA.z + __shfl_xor(zB.z, 8, 16); fA.w = zA.w + __shfl_xor(zB.w, 8, 16);
        fB.x = zB.x + __shfl_xor(zA.x, 8, 16); fB.y = zB.y + __shfl_xor(zA.y, 8, 16);
        fB.z = zB.z + __shfl_xor(zA.z, 8, 16); fB.w = zB.w + __shfl_xor(zA.w, 8, 16);
        fA.x *= inv; fA.y *= inv; fA.z *= inv; fA.w *= inv;
        fB.x *= inv; fB.y *= inv; fB.z *= inv; fB.w *= inv;
        if (rep == 0) {
            *(float4*)&qzb[h * 68 + ofsA] = fA;      // ofsA = c3*8
            *(float4*)&qzb[h * 68 + ofsB] = fB;      // ofsB = c3*8+4
        }

        // ---- OD: lane = d; od = sum_e z_{h(d)}[e] * Wv[e][d]  (canonical Wv4)
        float od = 0.f;
        #pragma unroll
        for (int e4 = 0; e4 < 16; ++e4) {
            const float4 z  = *(float4*)&qzb[h * 68 + e4 * 4];
            const float4 wv = *(float4*)&sWv4[e4 * 256 + lane * 4];
            od += z.x * wv.x + z.y * wv.y + z.z * wv.z + z.w * wv.w;
        }
        obb[lane] = od;

        // ---- merge1 via Pcat (LDS, canonical): hv[f] = [od||feat] @ Pcat[:,f]
        float hv = 0.f;
        #pragma unroll
        for (int e4 = 0; e4 < 12; ++e4) {
            float4 x;
            if (half == 0) x = *(float4*)&obb[e4 * 4];
            else x = (e4 < 4) ? *(float4*)&obb[48 + e4 * 4]
                              : *(float4*)&qfb[(e4 - 4) * 4];
            const float4 w4 = *(float4*)&sP4[(half * 12 + e4) * 128 + td * 4];
            hv += x.x * w4.x + x.y * w4.y + x.z * w4.z + x.w * w4.w;
        }
        hv += __shfl_xor(hv, 32);
        hv = fmaxf(hv + b1v, 0.0f);
        if (lane < 32) obb[td] = hv;     // alias hidden buffer onto obb[0..31]

        // ---- merge2 (LDS, canonical) + store
        float y = 0.f;
        #pragma unroll
        for (int e4 = 0; e4 < 4; ++e4) {
            const float4 x  = *(float4*)&obb[half * 16 + e4 * 4];
            const float4 w4 = *(float4*)&sm4[(half * 4 + e4) * 128 + td * 4];
            y += x.x * w4.x + x.y * w4.y + x.z * w4.z + x.w * w4.w;
        }
        y += __shfl_xor(y, 32);
        if (lane < 32)
            h_out[((size_t)curside * NPAIRS + curp) * F + td] = y + b2v;
    }
}

__global__ __launch_bounds__(256) void final_kernel(
    const float* __restrict__ h3,
    const float* __restrict__ aw1, const float* __restrict__ ab1,
    const float* __restrict__ aw2, const float* __restrict__ ab2,
    float* __restrict__ out)
{
    const int bidx = threadIdx.x;   // 256 threads, 1 block
    float x[64];
    #pragma unroll
    for (int e = 0; e < 32; ++e) {
        x[e]      = h3[(size_t)bidx * 32 + e];
        x[32 + e] = h3[((size_t)NP3 + bidx) * 32 + e];
    }
    float acc = ab2[0];
    for (int f = 0; f < 32; ++f) {
        float hv = ab1[f];
        #pragma unroll
        for (int e = 0; e < 64; ++e) hv += x[e] * aw1[e * 32 + f];
        acc += fmaxf(hv, 0.0f) * aw2[f];
    }
    out[bidx] = acc;
}

extern "C" void kernel_launch(void* const* d_in, const int* in_sizes, int n_in,
                              void* d_out, int out_size, void* d_ws, size_t ws_size,
                              hipStream_t stream)
{
    const int*   src_idx = (const int*)d_in[0];
    const int*   tgt_idx = (const int*)d_in[1];
    const float* cut     = (const float*)d_in[2];
    const float* emb   = (const float*)d_in[4];
    const float* freq  = (const float*)d_in[5];
    const float* phase = (const float*)d_in[6];
    const float* Wq    = (const float*)d_in[7];
    const float* Wk    = (const float*)d_in[8];
    const float* Wv    = (const float*)d_in[9];
    const float* Wo    = (const float*)d_in[10];
    const float* mw1   = (const float*)d_in[11];
    const float* mb1   = (const float*)d_in[12];
    const float* mw2   = (const float*)d_in[13];
    const float* mb2   = (const float*)d_in[14];
    const float* aw1   = (const float*)d_in[15];
    const float* ab1   = (const float*)d_in[16];
    const float* aw2   = (const float*)d_in[17];
    const float* ab2   = (const float*)d_in[18];

    float* ws = (float*)d_ws;
    float* h1 = ws + OFF_H1;
    float* h2 = ws + OFF_H2;
    float* h3 = ws + OFF_H3;

    const size_t smem_bytes = SMEM_FLOATS * sizeof(float);
    hipFuncSetAttribute((const void*)attn_kernel<1>, hipFuncAttributeMaxDynamicSharedMemorySize, (int)smem_bytes);
    hipFuncSetAttribute((const void*)attn_kernel<2>, hipFuncAttributeMaxDynamicSharedMemorySize, (int)smem_bytes);
    hipFuncSetAttribute((const void*)attn_kernel<3>, hipFuncAttributeMaxDynamicSharedMemorySize, (int)smem_bytes);

    transform_weights<<<dim3(3), dim3(256), 0, stream>>>(Wq, Wk, Wv, Wo, mw1, mw2, phase, ws);
    attn_kernel<1><<<dim3(256), dim3(768), smem_bytes, stream>>>(
        src_idx, tgt_idx, cut, emb, freq, phase, ws, mb1, mb2, (const float*)nullptr, h1);
    attn_kernel<2><<<dim3(256), dim3(768), smem_bytes, stream>>>(
        src_idx, tgt_idx, cut, emb, freq, phase, ws, mb1, mb2, h1, h2);
    attn_kernel<3><<<dim3(43), dim3(768), smem_bytes, stream>>>(
        src_idx, tgt_idx, cut, emb, freq, phase, ws, mb1, mb2, h2, h3);
    final_kernel<<<dim3(1), dim3(256), 0, stream>>>(h3, aw1, ab1, aw2, ab2, (float*)d_out);
}